// Round 11
// baseline (236.701 us; speedup 1.0000x reference)
//
#include <hip/hip_runtime.h>
#include <math.h>

#define LOD 64
#define LSD 128
#define KK 16
#define BB 128
#define TT 96
#define OBSD 128
#define ENC 512
#define CH 128
#define OUTD 64
#define TMP 132   // tm2 row pad

typedef short bf8v __attribute__((ext_vector_type(8)));   // 8 bf16 = 4 VGPR
typedef float f32x4 __attribute__((ext_vector_type(4)));

__device__ __forceinline__ float elup1f(float x) {
    return x >= 0.0f ? x + 1.0f : expf(x);
}

__device__ __forceinline__ unsigned short f2bf(float f) {
    union { float f; unsigned int u; } v; v.f = f;
    unsigned int r = (v.u + 0x7FFFu + ((v.u >> 16) & 1u)) >> 16;
    return (unsigned short)r;
}

// ---------------- prep: basis band-compress + weight transpose/cvt to bf16 ----------------
__global__ void prep_all(const float* __restrict__ tm11, const float* __restrict__ tm12,
                         const float* __restrict__ tm21, const float* __restrict__ tm22,
                         const float* __restrict__ enc_W,
                         const float* __restrict__ wmean_W, const float* __restrict__ wcov_W,
                         const float* __restrict__ varh_W, const float* __restrict__ dec_W,
                         const float* __restrict__ var_W,
                         float* __restrict__ basis,
                         unsigned short* __restrict__ encWt, unsigned short* __restrict__ w2t,
                         unsigned short* __restrict__ varhWt, unsigned short* __restrict__ decWt,
                         unsigned short* __restrict__ varWt) {
    int e = blockIdx.x * blockDim.x + threadIdx.x;
    if (e < 28672) {
        int k = e / (128 * 14);
        int rem = e % (128 * 14);
        int row = rem / 14;
        int s = rem % 14;
        int r = row & 63;
        int half = row >> 6;
        int sub = (s >= 7) ? 1 : 0;
        int ss = s - sub * 7;
        int col = r - 3 + ss;
        float v = 0.0f;
        if (col >= 0 && col < 64) {
            const float* src = half ? (sub ? tm22 : tm21) : (sub ? tm12 : tm11);
            v = src[k * 4096 + r * 64 + col];
        }
        basis[e] = v;
        return;
    }
    e -= 28672;
    if (e < 65536) {
        int n = e >> 7, k = e & 127;
        encWt[n * 128 + k] = f2bf(enc_W[k * 512 + n]);
        return;
    }
    e -= 65536;
    if (e < 65536) {
        int n = e >> 9, k = e & 511;
        float v = (n < 64) ? wmean_W[k * 64 + n] : wcov_W[k * 64 + (n - 64)];
        w2t[n * 512 + k] = f2bf(v);
        return;
    }
    e -= 65536;
    if (e < 16384) {
        int n = e >> 7, k = e & 127;
        varhWt[n * 128 + k] = f2bf(varh_W[k * 128 + n]);
        return;
    }
    e -= 16384;
    if (e < 8192) {
        int n = e >> 7, k = e & 127;
        decWt[n * 128 + k] = f2bf(dec_W[k * 64 + n]);
        return;
    }
    e -= 8192;
    if (e < 8192) {
        int n = e >> 7, k = e & 127;
        varWt[n * 128 + k] = f2bf(var_W[k * 64 + n]);
        return;
    }
}

// ---------------- encoder: MFMA bf16, 32 rows/block (unchanged from R10) ----------------
#define EBM 32
__global__ __launch_bounds__(256, 2)
void encoder_mfma(const float* __restrict__ obs, const unsigned short* __restrict__ encWt,
                  const float* __restrict__ enc_b, const unsigned short* __restrict__ w2t,
                  const float* __restrict__ wmean_b, const float* __restrict__ wcov_b,
                  float* __restrict__ wm_out, float* __restrict__ wc_out) {
    __shared__ __align__(16) unsigned short obs_s[EBM][136];
    __shared__ __align__(16) unsigned short h_s[EBM][520];
    __shared__ __align__(16) float g_s[EBM][136];

    int tid = threadIdx.x;
    int w = tid >> 6, l = tid & 63;
    int col = l & 15, kg = l >> 4;
    long row0 = (long)blockIdx.x * EBM;

    {
        int r = tid >> 3, seg = tid & 7;
        const float4* src = (const float4*)(obs + (row0 + r) * OBSD + seg * 16);
        float4 v0 = src[0], v1 = src[1], v2 = src[2], v3 = src[3];
        unsigned short* dst = &obs_s[r][seg * 16];
        dst[0] = f2bf(v0.x); dst[1] = f2bf(v0.y); dst[2] = f2bf(v0.z); dst[3] = f2bf(v0.w);
        dst[4] = f2bf(v1.x); dst[5] = f2bf(v1.y); dst[6] = f2bf(v1.z); dst[7] = f2bf(v1.w);
        dst[8] = f2bf(v2.x); dst[9] = f2bf(v2.y); dst[10] = f2bf(v2.z); dst[11] = f2bf(v2.w);
        dst[12] = f2bf(v3.x); dst[13] = f2bf(v3.y); dst[14] = f2bf(v3.z); dst[15] = f2bf(v3.w);
    }
    __syncthreads();

    f32x4 acc[2][8];
    #pragma unroll
    for (int mt = 0; mt < 2; ++mt)
        #pragma unroll
        for (int nt = 0; nt < 8; ++nt)
            acc[mt][nt] = (f32x4){0.f, 0.f, 0.f, 0.f};

    #pragma unroll
    for (int kc = 0; kc < 4; ++kc) {
        bf8v a0 = *(const bf8v*)&obs_s[col][kc * 32 + kg * 8];
        bf8v a1 = *(const bf8v*)&obs_s[16 + col][kc * 32 + kg * 8];
        #pragma unroll
        for (int nt = 0; nt < 8; ++nt) {
            int n0 = w * 128 + nt * 16;
            bf8v b = *(const bf8v*)&encWt[(n0 + col) * 128 + kc * 32 + kg * 8];
            acc[0][nt] = __builtin_amdgcn_mfma_f32_16x16x32_bf16(a0, b, acc[0][nt], 0, 0, 0);
            acc[1][nt] = __builtin_amdgcn_mfma_f32_16x16x32_bf16(a1, b, acc[1][nt], 0, 0, 0);
        }
    }
    #pragma unroll
    for (int nt = 0; nt < 8; ++nt) {
        int ccol = w * 128 + nt * 16 + col;
        float bia = enc_b[ccol];
        #pragma unroll
        for (int mt = 0; mt < 2; ++mt) {
            #pragma unroll
            for (int r = 0; r < 4; ++r) {
                int row = mt * 16 + kg * 4 + r;
                h_s[row][ccol] = f2bf(fmaxf(acc[mt][nt][r] + bia, 0.f));
            }
        }
    }
    __syncthreads();

    f32x4 acc2[2][2];
    #pragma unroll
    for (int mt = 0; mt < 2; ++mt)
        #pragma unroll
        for (int nt = 0; nt < 2; ++nt)
            acc2[mt][nt] = (f32x4){0.f, 0.f, 0.f, 0.f};

    #pragma unroll
    for (int kc = 0; kc < 16; ++kc) {
        bf8v a0 = *(const bf8v*)&h_s[col][kc * 32 + kg * 8];
        bf8v a1 = *(const bf8v*)&h_s[16 + col][kc * 32 + kg * 8];
        bf8v b0 = *(const bf8v*)&w2t[(w * 32 + col) * 512 + kc * 32 + kg * 8];
        bf8v b1 = *(const bf8v*)&w2t[(w * 32 + 16 + col) * 512 + kc * 32 + kg * 8];
        acc2[0][0] = __builtin_amdgcn_mfma_f32_16x16x32_bf16(a0, b0, acc2[0][0], 0, 0, 0);
        acc2[0][1] = __builtin_amdgcn_mfma_f32_16x16x32_bf16(a0, b1, acc2[0][1], 0, 0, 0);
        acc2[1][0] = __builtin_amdgcn_mfma_f32_16x16x32_bf16(a1, b0, acc2[1][0], 0, 0, 0);
        acc2[1][1] = __builtin_amdgcn_mfma_f32_16x16x32_bf16(a1, b1, acc2[1][1], 0, 0, 0);
    }
    #pragma unroll
    for (int nt = 0; nt < 2; ++nt) {
        int ccol = w * 32 + nt * 16 + col;
        float b2 = (ccol < 64) ? wmean_b[ccol] : wcov_b[ccol - 64];
        #pragma unroll
        for (int mt = 0; mt < 2; ++mt) {
            #pragma unroll
            for (int r = 0; r < 4; ++r) {
                int row = mt * 16 + kg * 4 + r;
                g_s[row][ccol] = acc2[mt][nt][r] + b2;
            }
        }
    }
    __syncthreads();

    {
        int r = tid >> 3, g = tid & 7;
        float ss = 0.f;
        for (int j = g; j < 64; j += 8) { float v = g_s[r][j]; ss += v * v; }
        ss += __shfl_xor(ss, 1, 64);
        ss += __shfl_xor(ss, 2, 64);
        ss += __shfl_xor(ss, 4, 64);
        float inv = 1.f / sqrtf(ss);
        for (int j = g; j < 64; j += 8) {
            wm_out[(row0 + r) * LOD + j] = g_s[r][j] * inv;
            wc_out[(row0 + r) * LOD + j] = elup1f(g_s[r][64 + j]);
        }
    }
}

// ---------------- scan: R8 structure + E-phase read hoisting ----------------
__global__ __launch_bounds__(256, 1)
void scan_kernel(const float* __restrict__ wm_g, const float* __restrict__ wc_g,
                 const float* __restrict__ cW1, const float* __restrict__ cb1,
                 const float* __restrict__ cW2, const float* __restrict__ cb2,
                 const float* __restrict__ basis, const float* __restrict__ log_tc,
                 float* __restrict__ post_g) {
    extern __shared__ __align__(16) float smem[];
    float* wm_l   = smem;            // 6144
    float* wc_l   = smem + 6144;     // 6144
    float* post_l = smem + 12288;    // 12288

    __shared__ __align__(16) float meanW[4][136];
    __shared__ __align__(16) float part_s[4][16];
    __shared__ float tm2[16 * TMP];

    int tid = threadIdx.x;
    int b = blockIdx.x;
    int w = tid >> 6;
    int l = tid & 63;
    int k = l & 15;
    int p = l >> 4;

    {
        const float4* s0 = (const float4*)(wm_g + (long)b * (TT * 64));
        const float4* s1 = (const float4*)(wc_g + (long)b * (TT * 64));
        float4* d0 = (float4*)wm_l;
        float4* d1 = (float4*)wc_l;
        for (int idx = tid; idx < TT * 64 / 4; idx += 256) {
            d0[idx] = s0[idx];
            d1[idx] = s1[idx];
        }
    }

    float br[16][7];
    #pragma unroll
    for (int q = 0; q < 16; ++q)
        #pragma unroll
        for (int j = 0; j < 7; ++j)
            br[q][j] = basis[q * 1792 + 7 * tid + j];

    int c = 32 * w + (l & 31);
    int jhalf = (l >= 32) ? 64 : 0;
    float w1r[64];
    #pragma unroll
    for (int jj = 0; jj < 64; ++jj)
        w1r[jj] = cW1[(jhalf + jj) * 128 + c];
    float cb1r = cb1[c];

    float w2r[8];
    #pragma unroll
    for (int u = 0; u < 8; ++u)
        w2r[u] = cW2[(32 * w + 8 * p + u) * 16 + k];
    float cb2r = cb2[k];

    float cuR = 10.f, clR = 10.f, csR = 0.f;
    float tcu_r = elup1f(log_tc[l]);
    float tcl_r = elup1f(log_tc[64 + l]);

    for (int idx = l; idx < 136; idx += 64) meanW[w][idx] = 0.f;
    __syncthreads();

    #pragma clang loop unroll(disable)
    for (int t = 0; t < TT; ++t) {
        float wmv = wm_l[t * 64 + l];
        float wcv = wc_l[t * 64 + l];
        float muw[7], mlw[7];
        #pragma unroll
        for (int d = 0; d < 7; ++d) {
            muw[d] = meanW[w][4 + l + d - 3];
            mlw[d] = meanW[w][68 + l + d - 3];
        }

        // ---- A ----
        float hh;
        {
            const float4* mq = (const float4*)(&meanW[w][4 + jhalf]);
            float a0 = 0.f, a1 = 0.f, a2 = 0.f, a3 = 0.f;
            #pragma unroll
            for (int j4 = 0; j4 < 16; ++j4) {
                float4 m4 = mq[j4];
                a0 += m4.x * w1r[4 * j4 + 0];
                a1 += m4.y * w1r[4 * j4 + 1];
                a2 += m4.z * w1r[4 * j4 + 2];
                a3 += m4.w * w1r[4 * j4 + 3];
            }
            float acc = (a0 + a1) + (a2 + a3);
            acc += __shfl_xor(acc, 32, 64);
            hh = fmaxf(acc + cb1r, 0.f);
        }

        // ---- B ----
        {
            float pl = 0.f;
            #pragma unroll
            for (int u = 0; u < 8; ++u)
                pl += __shfl(hh, 8 * p + u, 64) * w2r[u];
            pl += __shfl_xor(pl, 16, 64);
            pl += __shfl_xor(pl, 32, 64);
            if (l < 16) part_s[w][l] = pl + ((w == 0) ? cb2r : 0.f);
        }
        __syncthreads();   // BAR 1

        // ---- C ----
        float ck[16];
        {
            const float4* pq = (const float4*)(&part_s[0][0]);
            float sm = 0.f;
            #pragma unroll
            for (int g = 0; g < 4; ++g) {
                float4 a = pq[g], b2 = pq[4 + g], c2 = pq[8 + g], d2 = pq[12 + g];
                float e0 = __expf(a.x + b2.x + c2.x + d2.x);
                float e1 = __expf(a.y + b2.y + c2.y + d2.y);
                float e2 = __expf(a.z + b2.z + c2.z + d2.z);
                float e3 = __expf(a.w + b2.w + c2.w + d2.w);
                ck[4 * g + 0] = e0; ck[4 * g + 1] = e1;
                ck[4 * g + 2] = e2; ck[4 * g + 3] = e3;
                sm += (e0 + e1) + (e2 + e3);
            }
            float inv = 1.f / sm;
            #pragma unroll
            for (int q = 0; q < 16; ++q) ck[q] *= inv;
        }

        // ---- D ----
        {
            int r = tid >> 1;
            int s0 = (tid & 1) * 7;
            #pragma unroll
            for (int j = 0; j < 7; ++j) {
                float acc = 0.f;
                #pragma unroll
                for (int q = 0; q < 16; ++q) acc += ck[q] * br[q][j];
                tm2[(s0 + j) * TMP + r] = acc;
            }
        }
        __syncthreads();   // BAR 2

        // ---- E: hoisted tm2 reads -> carry shuffles -> math ----
        {
            int i = l;
            // (1) issue ALL tm2 reads back-to-back (latency overlaps shuffle issue below)
            float ua[7], ub[7], la[7], lb[7];
            #pragma unroll
            for (int s = 0; s < 7; ++s) {
                ua[s] = tm2[s * TMP + i];
                ub[s] = tm2[(7 + s) * TMP + i];
                la[s] = tm2[s * TMP + 64 + i];
                lb[s] = tm2[(7 + s) * TMP + 64 + i];
            }
            // (2) carry neighbor taps via shuffles
            float cun[7], csn[7], cln[7];
            #pragma unroll
            for (int d = 0; d < 7; ++d) {
                int src = i + d - 3;
                cun[d] = __shfl(cuR, src, 64);
                csn[d] = __shfl(csR, src, 64);
                cln[d] = __shfl(clR, src, 64);
            }
            // (3) arithmetic on resident registers
            float ncu = tcu_r, ncl = tcl_r, ncs = 0.f, au = 0.f, al = 0.f;
            #pragma unroll
            for (int s = 0; s < 7; ++s) {
                float A = ua[s], Bv = ub[s], C = la[s], D = lb[s];
                float cu = cun[s], cs = csn[s], cl = cln[s];
                ncu += A * A * cu + 2.f * A * Bv * cs + Bv * Bv * cl;
                ncl += C * C * cu + 2.f * C * D * cs + D * D * cl;
                ncs += C * A * cu + (D * A + C * Bv) * cs + D * Bv * cl;
                au += A * muw[s] + Bv * mlw[s];
                al += C * muw[s] + D * mlw[s];
            }
            float denom = ncu + wcv;
            float inv = 1.f / denom;
            float qu = ncu * inv, ql = ncs * inv;
            float res = wmv - au;
            float pmu = au + qu * res;
            float pml = al + ql * res;
            float cf = 1.f - qu;
            cuR = cf * ncu;
            clR = ncl - ql * ncs;
            csR = cf * ncs;
            meanW[w][4 + i] = pmu;
            meanW[w][68 + i] = pml;
            if (w == 0) {
                post_l[t * 128 + i] = pmu;
                post_l[t * 128 + 64 + i] = pml;
            }
        }
    }

    __syncthreads();
    {
        const float4* s0 = (const float4*)post_l;
        float4* d0 = (float4*)(post_g + (long)b * (TT * 128));
        for (int idx = tid; idx < TT * 128 / 4; idx += 256)
            d0[idx] = s0[idx];
    }
}

// ---------------- decoder: MFMA bf16 (unchanged from R10) ----------------
#define DBM 32
__global__ __launch_bounds__(256, 2)
void decoder_mfma(const float* __restrict__ post,
                  const unsigned short* __restrict__ decWt, const float* __restrict__ dec_b,
                  const unsigned short* __restrict__ varhWt, const float* __restrict__ varh_b,
                  const unsigned short* __restrict__ varWt, const float* __restrict__ var_b,
                  float* __restrict__ out) {
    __shared__ __align__(16) unsigned short post_s[DBM][136];
    __shared__ __align__(16) unsigned short vh_s[DBM][136];

    int tid = threadIdx.x;
    int w = tid >> 6, l = tid & 63;
    int col = l & 15, kg = l >> 4;
    long row0 = (long)blockIdx.x * DBM;

    {
        int r = tid >> 3, seg = tid & 7;
        const float4* src = (const float4*)(post + (row0 + r) * LSD + seg * 16);
        float4 v0 = src[0], v1 = src[1], v2 = src[2], v3 = src[3];
        unsigned short* dst = &post_s[r][seg * 16];
        dst[0] = f2bf(v0.x); dst[1] = f2bf(v0.y); dst[2] = f2bf(v0.z); dst[3] = f2bf(v0.w);
        dst[4] = f2bf(v1.x); dst[5] = f2bf(v1.y); dst[6] = f2bf(v1.z); dst[7] = f2bf(v1.w);
        dst[8] = f2bf(v2.x); dst[9] = f2bf(v2.y); dst[10] = f2bf(v2.z); dst[11] = f2bf(v2.w);
        dst[12] = f2bf(v3.x); dst[13] = f2bf(v3.y); dst[14] = f2bf(v3.z); dst[15] = f2bf(v3.w);
    }
    __syncthreads();

    f32x4 accA[2][2];
    #pragma unroll
    for (int mt = 0; mt < 2; ++mt)
        #pragma unroll
        for (int nt = 0; nt < 2; ++nt)
            accA[mt][nt] = (f32x4){0.f, 0.f, 0.f, 0.f};
    #pragma unroll
    for (int kc = 0; kc < 4; ++kc) {
        bf8v a0 = *(const bf8v*)&post_s[col][kc * 32 + kg * 8];
        bf8v a1 = *(const bf8v*)&post_s[16 + col][kc * 32 + kg * 8];
        bf8v b0 = *(const bf8v*)&varhWt[(w * 32 + col) * 128 + kc * 32 + kg * 8];
        bf8v b1 = *(const bf8v*)&varhWt[(w * 32 + 16 + col) * 128 + kc * 32 + kg * 8];
        accA[0][0] = __builtin_amdgcn_mfma_f32_16x16x32_bf16(a0, b0, accA[0][0], 0, 0, 0);
        accA[0][1] = __builtin_amdgcn_mfma_f32_16x16x32_bf16(a0, b1, accA[0][1], 0, 0, 0);
        accA[1][0] = __builtin_amdgcn_mfma_f32_16x16x32_bf16(a1, b0, accA[1][0], 0, 0, 0);
        accA[1][1] = __builtin_amdgcn_mfma_f32_16x16x32_bf16(a1, b1, accA[1][1], 0, 0, 0);
    }
    #pragma unroll
    for (int nt = 0; nt < 2; ++nt) {
        int ccol = w * 32 + nt * 16 + col;
        float bia = varh_b[ccol];
        #pragma unroll
        for (int mt = 0; mt < 2; ++mt)
            #pragma unroll
            for (int r = 0; r < 4; ++r) {
                int row = mt * 16 + kg * 4 + r;
                vh_s[row][ccol] = f2bf(fmaxf(accA[mt][nt][r] + bia, 0.f));
            }
    }
    __syncthreads();

    f32x4 accM[2], accV[2];
    #pragma unroll
    for (int mt = 0; mt < 2; ++mt) { accM[mt] = (f32x4){0.f,0.f,0.f,0.f}; accV[mt] = (f32x4){0.f,0.f,0.f,0.f}; }
    #pragma unroll
    for (int kc = 0; kc < 4; ++kc) {
        bf8v a0 = *(const bf8v*)&post_s[col][kc * 32 + kg * 8];
        bf8v a1 = *(const bf8v*)&post_s[16 + col][kc * 32 + kg * 8];
        bf8v v0 = *(const bf8v*)&vh_s[col][kc * 32 + kg * 8];
        bf8v v1 = *(const bf8v*)&vh_s[16 + col][kc * 32 + kg * 8];
        bf8v bm = *(const bf8v*)&decWt[(w * 16 + col) * 128 + kc * 32 + kg * 8];
        bf8v bv = *(const bf8v*)&varWt[(w * 16 + col) * 128 + kc * 32 + kg * 8];
        accM[0] = __builtin_amdgcn_mfma_f32_16x16x32_bf16(a0, bm, accM[0], 0, 0, 0);
        accM[1] = __builtin_amdgcn_mfma_f32_16x16x32_bf16(a1, bm, accM[1], 0, 0, 0);
        accV[0] = __builtin_amdgcn_mfma_f32_16x16x32_bf16(v0, bv, accV[0], 0, 0, 0);
        accV[1] = __builtin_amdgcn_mfma_f32_16x16x32_bf16(v1, bv, accV[1], 0, 0, 0);
    }
    {
        int ccol = w * 16 + col;
        float bm = dec_b[ccol];
        float bv = var_b[ccol];
        #pragma unroll
        for (int mt = 0; mt < 2; ++mt)
            #pragma unroll
            for (int r = 0; r < 4; ++r) {
                long row = row0 + mt * 16 + kg * 4 + r;
                out[row * 128 + ccol] = accM[mt][r] + bm;
                out[row * 128 + 64 + ccol] = elup1f(accV[mt][r] + bv);
            }
    }
}

extern "C" void kernel_launch(void* const* d_in, const int* in_sizes, int n_in,
                              void* d_out, int out_size, void* d_ws, size_t ws_size,
                              hipStream_t stream) {
    const float* obs     = (const float*)d_in[0];
    const float* enc_W   = (const float*)d_in[1];
    const float* enc_b   = (const float*)d_in[2];
    const float* wmean_W = (const float*)d_in[3];
    const float* wmean_b = (const float*)d_in[4];
    const float* wcov_W  = (const float*)d_in[5];
    const float* wcov_b  = (const float*)d_in[6];
    const float* cW1     = (const float*)d_in[7];
    const float* cb1     = (const float*)d_in[8];
    const float* cW2     = (const float*)d_in[9];
    const float* cb2     = (const float*)d_in[10];
    const float* tm11    = (const float*)d_in[11];
    const float* tm12    = (const float*)d_in[12];
    const float* tm21    = (const float*)d_in[13];
    const float* tm22    = (const float*)d_in[14];
    const float* log_tc  = (const float*)d_in[15];
    const float* dec_W   = (const float*)d_in[16];
    const float* dec_b   = (const float*)d_in[17];
    const float* varh_W  = (const float*)d_in[18];
    const float* varh_b  = (const float*)d_in[19];
    const float* var_W   = (const float*)d_in[20];
    const float* var_b   = (const float*)d_in[21];

    float* out = (float*)d_out;
    float* ws = (float*)d_ws;
    float* wm_ws    = ws;                 // 786432
    float* wc_ws    = ws + 786432;        // 786432
    float* post_ws  = ws + 1572864;       // 1572864
    float* basis_ws = ws + 3145728;       // 28672
    unsigned short* encWt_bf  = (unsigned short*)(ws + 3174400);  // 65536 sh
    unsigned short* w2t_bf    = (unsigned short*)(ws + 3207168);  // 65536 sh
    unsigned short* varhWt_bf = (unsigned short*)(ws + 3239936);  // 16384 sh
    unsigned short* decWt_bf  = (unsigned short*)(ws + 3248128);  // 8192 sh
    unsigned short* varWt_bf  = (unsigned short*)(ws + 3252224);  // 8192 sh

    size_t dyn = (size_t)(6144 + 6144 + 12288) * sizeof(float);  // 98304 B
    (void)hipFuncSetAttribute((const void*)scan_kernel,
                              hipFuncAttributeMaxDynamicSharedMemorySize,
                              (int)dyn);

    prep_all<<<752, 256, 0, stream>>>(tm11, tm12, tm21, tm22, enc_W, wmean_W, wcov_W,
                                      varh_W, dec_W, var_W, basis_ws,
                                      encWt_bf, w2t_bf, varhWt_bf, decWt_bf, varWt_bf);
    encoder_mfma<<<384, 256, 0, stream>>>(obs, encWt_bf, enc_b, w2t_bf,
                                          wmean_b, wcov_b, wm_ws, wc_ws);
    scan_kernel<<<128, 256, dyn, stream>>>(wm_ws, wc_ws, cW1, cb1, cW2, cb2,
                                           basis_ws, log_tc, post_ws);
    decoder_mfma<<<384, 256, 0, stream>>>(post_ws, decWt_bf, dec_b, varhWt_bf, varh_b,
                                          varWt_bf, var_b, out);
}

// Round 12
// 230.135 us; speedup vs baseline: 1.0285x; 1.0285x over previous
//
#include <hip/hip_runtime.h>
#include <math.h>

#define LOD 64
#define LSD 128
#define KK 16
#define BB 128
#define TT 96
#define OBSD 128
#define ENC 512
#define CH 128
#define OUTD 64
#define TMP 132   // tm2 row pad

typedef short bf8v __attribute__((ext_vector_type(8)));   // 8 bf16 = 4 VGPR
typedef float f32x4 __attribute__((ext_vector_type(4)));

__device__ __forceinline__ float elup1f(float x) {
    return x >= 0.0f ? x + 1.0f : expf(x);
}

__device__ __forceinline__ unsigned short f2bf(float f) {
    union { float f; unsigned int u; } v; v.f = f;
    unsigned int r = (v.u + 0x7FFFu + ((v.u >> 16) & 1u)) >> 16;
    return (unsigned short)r;
}

// ---------------- prep: basis band-compress + weight transpose/cvt to bf16 ----------------
__global__ void prep_all(const float* __restrict__ tm11, const float* __restrict__ tm12,
                         const float* __restrict__ tm21, const float* __restrict__ tm22,
                         const float* __restrict__ enc_W,
                         const float* __restrict__ wmean_W, const float* __restrict__ wcov_W,
                         const float* __restrict__ varh_W, const float* __restrict__ dec_W,
                         const float* __restrict__ var_W,
                         float* __restrict__ basis,
                         unsigned short* __restrict__ encWt, unsigned short* __restrict__ w2t,
                         unsigned short* __restrict__ varhWt, unsigned short* __restrict__ decWt,
                         unsigned short* __restrict__ varWt) {
    int e = blockIdx.x * blockDim.x + threadIdx.x;
    if (e < 28672) {
        int k = e / (128 * 14);
        int rem = e % (128 * 14);
        int row = rem / 14;
        int s = rem % 14;
        int r = row & 63;
        int half = row >> 6;
        int sub = (s >= 7) ? 1 : 0;
        int ss = s - sub * 7;
        int col = r - 3 + ss;
        float v = 0.0f;
        if (col >= 0 && col < 64) {
            const float* src = half ? (sub ? tm22 : tm21) : (sub ? tm12 : tm11);
            v = src[k * 4096 + r * 64 + col];
        }
        basis[e] = v;
        return;
    }
    e -= 28672;
    if (e < 65536) {
        int n = e >> 7, k = e & 127;
        encWt[n * 128 + k] = f2bf(enc_W[k * 512 + n]);
        return;
    }
    e -= 65536;
    if (e < 65536) {
        int n = e >> 9, k = e & 511;
        float v = (n < 64) ? wmean_W[k * 64 + n] : wcov_W[k * 64 + (n - 64)];
        w2t[n * 512 + k] = f2bf(v);
        return;
    }
    e -= 65536;
    if (e < 16384) {
        int n = e >> 7, k = e & 127;
        varhWt[n * 128 + k] = f2bf(varh_W[k * 128 + n]);
        return;
    }
    e -= 16384;
    if (e < 8192) {
        int n = e >> 7, k = e & 127;
        decWt[n * 128 + k] = f2bf(dec_W[k * 64 + n]);
        return;
    }
    e -= 8192;
    if (e < 8192) {
        int n = e >> 7, k = e & 127;
        varWt[n * 128 + k] = f2bf(var_W[k * 64 + n]);
        return;
    }
}

// ---------------- encoder: MFMA bf16, 32 rows/block ----------------
#define EBM 32
__global__ __launch_bounds__(256, 2)
void encoder_mfma(const float* __restrict__ obs, const unsigned short* __restrict__ encWt,
                  const float* __restrict__ enc_b, const unsigned short* __restrict__ w2t,
                  const float* __restrict__ wmean_b, const float* __restrict__ wcov_b,
                  float* __restrict__ wm_out, float* __restrict__ wc_out) {
    __shared__ __align__(16) unsigned short obs_s[EBM][136];
    __shared__ __align__(16) unsigned short h_s[EBM][520];
    __shared__ __align__(16) float g_s[EBM][136];

    int tid = threadIdx.x;
    int w = tid >> 6, l = tid & 63;
    int col = l & 15, kg = l >> 4;
    long row0 = (long)blockIdx.x * EBM;

    {
        int r = tid >> 3, seg = tid & 7;
        const float4* src = (const float4*)(obs + (row0 + r) * OBSD + seg * 16);
        float4 v0 = src[0], v1 = src[1], v2 = src[2], v3 = src[3];
        unsigned short* dst = &obs_s[r][seg * 16];
        dst[0] = f2bf(v0.x); dst[1] = f2bf(v0.y); dst[2] = f2bf(v0.z); dst[3] = f2bf(v0.w);
        dst[4] = f2bf(v1.x); dst[5] = f2bf(v1.y); dst[6] = f2bf(v1.z); dst[7] = f2bf(v1.w);
        dst[8] = f2bf(v2.x); dst[9] = f2bf(v2.y); dst[10] = f2bf(v2.z); dst[11] = f2bf(v2.w);
        dst[12] = f2bf(v3.x); dst[13] = f2bf(v3.y); dst[14] = f2bf(v3.z); dst[15] = f2bf(v3.w);
    }
    __syncthreads();

    f32x4 acc[2][8];
    #pragma unroll
    for (int mt = 0; mt < 2; ++mt)
        #pragma unroll
        for (int nt = 0; nt < 8; ++nt)
            acc[mt][nt] = (f32x4){0.f, 0.f, 0.f, 0.f};

    #pragma unroll
    for (int kc = 0; kc < 4; ++kc) {
        bf8v a0 = *(const bf8v*)&obs_s[col][kc * 32 + kg * 8];
        bf8v a1 = *(const bf8v*)&obs_s[16 + col][kc * 32 + kg * 8];
        #pragma unroll
        for (int nt = 0; nt < 8; ++nt) {
            int n0 = w * 128 + nt * 16;
            bf8v b = *(const bf8v*)&encWt[(n0 + col) * 128 + kc * 32 + kg * 8];
            acc[0][nt] = __builtin_amdgcn_mfma_f32_16x16x32_bf16(a0, b, acc[0][nt], 0, 0, 0);
            acc[1][nt] = __builtin_amdgcn_mfma_f32_16x16x32_bf16(a1, b, acc[1][nt], 0, 0, 0);
        }
    }
    #pragma unroll
    for (int nt = 0; nt < 8; ++nt) {
        int ccol = w * 128 + nt * 16 + col;
        float bia = enc_b[ccol];
        #pragma unroll
        for (int mt = 0; mt < 2; ++mt) {
            #pragma unroll
            for (int r = 0; r < 4; ++r) {
                int row = mt * 16 + kg * 4 + r;
                h_s[row][ccol] = f2bf(fmaxf(acc[mt][nt][r] + bia, 0.f));
            }
        }
    }
    __syncthreads();

    f32x4 acc2[2][2];
    #pragma unroll
    for (int mt = 0; mt < 2; ++mt)
        #pragma unroll
        for (int nt = 0; nt < 2; ++nt)
            acc2[mt][nt] = (f32x4){0.f, 0.f, 0.f, 0.f};

    #pragma unroll
    for (int kc = 0; kc < 16; ++kc) {
        bf8v a0 = *(const bf8v*)&h_s[col][kc * 32 + kg * 8];
        bf8v a1 = *(const bf8v*)&h_s[16 + col][kc * 32 + kg * 8];
        bf8v b0 = *(const bf8v*)&w2t[(w * 32 + col) * 512 + kc * 32 + kg * 8];
        bf8v b1 = *(const bf8v*)&w2t[(w * 32 + 16 + col) * 512 + kc * 32 + kg * 8];
        acc2[0][0] = __builtin_amdgcn_mfma_f32_16x16x32_bf16(a0, b0, acc2[0][0], 0, 0, 0);
        acc2[0][1] = __builtin_amdgcn_mfma_f32_16x16x32_bf16(a0, b1, acc2[0][1], 0, 0, 0);
        acc2[1][0] = __builtin_amdgcn_mfma_f32_16x16x32_bf16(a1, b0, acc2[1][0], 0, 0, 0);
        acc2[1][1] = __builtin_amdgcn_mfma_f32_16x16x32_bf16(a1, b1, acc2[1][1], 0, 0, 0);
    }
    #pragma unroll
    for (int nt = 0; nt < 2; ++nt) {
        int ccol = w * 32 + nt * 16 + col;
        float b2 = (ccol < 64) ? wmean_b[ccol] : wcov_b[ccol - 64];
        #pragma unroll
        for (int mt = 0; mt < 2; ++mt) {
            #pragma unroll
            for (int r = 0; r < 4; ++r) {
                int row = mt * 16 + kg * 4 + r;
                g_s[row][ccol] = acc2[mt][nt][r] + b2;
            }
        }
    }
    __syncthreads();

    {
        int r = tid >> 3, g = tid & 7;
        float ss = 0.f;
        for (int j = g; j < 64; j += 8) { float v = g_s[r][j]; ss += v * v; }
        ss += __shfl_xor(ss, 1, 64);
        ss += __shfl_xor(ss, 2, 64);
        ss += __shfl_xor(ss, 4, 64);
        float inv = 1.f / sqrtf(ss);
        for (int j = g; j < 64; j += 8) {
            wm_out[(row0 + r) * LOD + j] = g_s[r][j] * inv;
            wc_out[(row0 + r) * LOD + j] = elup1f(g_s[r][64 + j]);
        }
    }
}

// ---------------- scan: R8 structure (4 waves, 2 barriers, redundant E) ----------------
__global__ __launch_bounds__(256, 1)
void scan_kernel(const float* __restrict__ wm_g, const float* __restrict__ wc_g,
                 const float* __restrict__ cW1, const float* __restrict__ cb1,
                 const float* __restrict__ cW2, const float* __restrict__ cb2,
                 const float* __restrict__ basis, const float* __restrict__ log_tc,
                 float* __restrict__ post_g) {
    extern __shared__ __align__(16) float smem[];
    float* wm_l   = smem;            // 6144
    float* wc_l   = smem + 6144;     // 6144
    float* post_l = smem + 12288;    // 12288

    __shared__ __align__(16) float meanW[4][136];
    __shared__ __align__(16) float part_s[4][16];
    __shared__ float tm2[16 * TMP];

    int tid = threadIdx.x;
    int b = blockIdx.x;
    int w = tid >> 6;
    int l = tid & 63;
    int k = l & 15;
    int p = l >> 4;

    {
        const float4* s0 = (const float4*)(wm_g + (long)b * (TT * 64));
        const float4* s1 = (const float4*)(wc_g + (long)b * (TT * 64));
        float4* d0 = (float4*)wm_l;
        float4* d1 = (float4*)wc_l;
        for (int idx = tid; idx < TT * 64 / 4; idx += 256) {
            d0[idx] = s0[idx];
            d1[idx] = s1[idx];
        }
    }

    float br[16][7];
    #pragma unroll
    for (int q = 0; q < 16; ++q)
        #pragma unroll
        for (int j = 0; j < 7; ++j)
            br[q][j] = basis[q * 1792 + 7 * tid + j];

    int c = 32 * w + (l & 31);
    int jhalf = (l >= 32) ? 64 : 0;
    float w1r[64];
    #pragma unroll
    for (int jj = 0; jj < 64; ++jj)
        w1r[jj] = cW1[(jhalf + jj) * 128 + c];
    float cb1r = cb1[c];

    float w2r[8];
    #pragma unroll
    for (int u = 0; u < 8; ++u)
        w2r[u] = cW2[(32 * w + 8 * p + u) * 16 + k];
    float cb2r = cb2[k];

    float cuR = 10.f, clR = 10.f, csR = 0.f;
    float tcu_r = elup1f(log_tc[l]);
    float tcl_r = elup1f(log_tc[64 + l]);

    for (int idx = l; idx < 136; idx += 64) meanW[w][idx] = 0.f;
    __syncthreads();

    #pragma clang loop unroll(disable)
    for (int t = 0; t < TT; ++t) {
        float wmv = wm_l[t * 64 + l];
        float wcv = wc_l[t * 64 + l];
        float muw[7], mlw[7];
        #pragma unroll
        for (int d = 0; d < 7; ++d) {
            muw[d] = meanW[w][4 + l + d - 3];
            mlw[d] = meanW[w][68 + l + d - 3];
        }

        // ---- A ----
        float hh;
        {
            const float4* mq = (const float4*)(&meanW[w][4 + jhalf]);
            float a0 = 0.f, a1 = 0.f, a2 = 0.f, a3 = 0.f;
            #pragma unroll
            for (int j4 = 0; j4 < 16; ++j4) {
                float4 m4 = mq[j4];
                a0 += m4.x * w1r[4 * j4 + 0];
                a1 += m4.y * w1r[4 * j4 + 1];
                a2 += m4.z * w1r[4 * j4 + 2];
                a3 += m4.w * w1r[4 * j4 + 3];
            }
            float acc = (a0 + a1) + (a2 + a3);
            acc += __shfl_xor(acc, 32, 64);
            hh = fmaxf(acc + cb1r, 0.f);
        }

        // ---- B ----
        {
            float pl = 0.f;
            #pragma unroll
            for (int u = 0; u < 8; ++u)
                pl += __shfl(hh, 8 * p + u, 64) * w2r[u];
            pl += __shfl_xor(pl, 16, 64);
            pl += __shfl_xor(pl, 32, 64);
            if (l < 16) part_s[w][l] = pl + ((w == 0) ? cb2r : 0.f);
        }
        __syncthreads();   // BAR 1

        // ---- C ----
        float ck[16];
        {
            const float4* pq = (const float4*)(&part_s[0][0]);
            float sm = 0.f;
            #pragma unroll
            for (int g = 0; g < 4; ++g) {
                float4 a = pq[g], b2 = pq[4 + g], c2 = pq[8 + g], d2 = pq[12 + g];
                float e0 = __expf(a.x + b2.x + c2.x + d2.x);
                float e1 = __expf(a.y + b2.y + c2.y + d2.y);
                float e2 = __expf(a.z + b2.z + c2.z + d2.z);
                float e3 = __expf(a.w + b2.w + c2.w + d2.w);
                ck[4 * g + 0] = e0; ck[4 * g + 1] = e1;
                ck[4 * g + 2] = e2; ck[4 * g + 3] = e3;
                sm += (e0 + e1) + (e2 + e3);
            }
            float inv = 1.f / sm;
            #pragma unroll
            for (int q = 0; q < 16; ++q) ck[q] *= inv;
        }

        // ---- D ----
        {
            int r = tid >> 1;
            int s0 = (tid & 1) * 7;
            #pragma unroll
            for (int j = 0; j < 7; ++j) {
                float acc = 0.f;
                #pragma unroll
                for (int q = 0; q < 16; ++q) acc += ck[q] * br[q][j];
                tm2[(s0 + j) * TMP + r] = acc;
            }
        }
        __syncthreads();   // BAR 2

        // ---- E ----
        {
            int i = l;
            float cun[7], csn[7], cln[7];
            #pragma unroll
            for (int d = 0; d < 7; ++d) {
                int src = i + d - 3;
                cun[d] = __shfl(cuR, src, 64);
                csn[d] = __shfl(csR, src, 64);
                cln[d] = __shfl(clR, src, 64);
            }
            float ncu = tcu_r, ncl = tcl_r, ncs = 0.f, au = 0.f, al = 0.f;
            #pragma unroll
            for (int s = 0; s < 7; ++s) {
                float A  = tm2[s * TMP + i];
                float Bv = tm2[(7 + s) * TMP + i];
                float C  = tm2[s * TMP + 64 + i];
                float D  = tm2[(7 + s) * TMP + 64 + i];
                float cu = cun[s], cs = csn[s], cl = cln[s];
                ncu += A * A * cu + 2.f * A * Bv * cs + Bv * Bv * cl;
                ncl += C * C * cu + 2.f * C * D * cs + D * D * cl;
                ncs += C * A * cu + (D * A + C * Bv) * cs + D * Bv * cl;
                au += A * muw[s] + Bv * mlw[s];
                al += C * muw[s] + D * mlw[s];
            }
            float denom = ncu + wcv;
            float inv = 1.f / denom;
            float qu = ncu * inv, ql = ncs * inv;
            float res = wmv - au;
            float pmu = au + qu * res;
            float pml = al + ql * res;
            float cf = 1.f - qu;
            cuR = cf * ncu;
            clR = ncl - ql * ncs;
            csR = cf * ncs;
            meanW[w][4 + i] = pmu;
            meanW[w][68 + i] = pml;
            if (w == 0) {
                post_l[t * 128 + i] = pmu;
                post_l[t * 128 + 64 + i] = pml;
            }
        }
    }

    __syncthreads();
    {
        const float4* s0 = (const float4*)post_l;
        float4* d0 = (float4*)(post_g + (long)b * (TT * 128));
        for (int idx = tid; idx < TT * 128 / 4; idx += 256)
            d0[idx] = s0[idx];
    }
}

// ---------------- decoder: MFMA bf16, 32 rows/block ----------------
#define DBM 32
__global__ __launch_bounds__(256, 2)
void decoder_mfma(const float* __restrict__ post,
                  const unsigned short* __restrict__ decWt, const float* __restrict__ dec_b,
                  const unsigned short* __restrict__ varhWt, const float* __restrict__ varh_b,
                  const unsigned short* __restrict__ varWt, const float* __restrict__ var_b,
                  float* __restrict__ out) {
    __shared__ __align__(16) unsigned short post_s[DBM][136];
    __shared__ __align__(16) unsigned short vh_s[DBM][136];

    int tid = threadIdx.x;
    int w = tid >> 6, l = tid & 63;
    int col = l & 15, kg = l >> 4;
    long row0 = (long)blockIdx.x * DBM;

    {
        int r = tid >> 3, seg = tid & 7;
        const float4* src = (const float4*)(post + (row0 + r) * LSD + seg * 16);
        float4 v0 = src[0], v1 = src[1], v2 = src[2], v3 = src[3];
        unsigned short* dst = &post_s[r][seg * 16];
        dst[0] = f2bf(v0.x); dst[1] = f2bf(v0.y); dst[2] = f2bf(v0.z); dst[3] = f2bf(v0.w);
        dst[4] = f2bf(v1.x); dst[5] = f2bf(v1.y); dst[6] = f2bf(v1.z); dst[7] = f2bf(v1.w);
        dst[8] = f2bf(v2.x); dst[9] = f2bf(v2.y); dst[10] = f2bf(v2.z); dst[11] = f2bf(v2.w);
        dst[12] = f2bf(v3.x); dst[13] = f2bf(v3.y); dst[14] = f2bf(v3.z); dst[15] = f2bf(v3.w);
    }
    __syncthreads();

    f32x4 accA[2][2];
    #pragma unroll
    for (int mt = 0; mt < 2; ++mt)
        #pragma unroll
        for (int nt = 0; nt < 2; ++nt)
            accA[mt][nt] = (f32x4){0.f, 0.f, 0.f, 0.f};
    #pragma unroll
    for (int kc = 0; kc < 4; ++kc) {
        bf8v a0 = *(const bf8v*)&post_s[col][kc * 32 + kg * 8];
        bf8v a1 = *(const bf8v*)&post_s[16 + col][kc * 32 + kg * 8];
        bf8v b0 = *(const bf8v*)&varhWt[(w * 32 + col) * 128 + kc * 32 + kg * 8];
        bf8v b1 = *(const bf8v*)&varhWt[(w * 32 + 16 + col) * 128 + kc * 32 + kg * 8];
        accA[0][0] = __builtin_amdgcn_mfma_f32_16x16x32_bf16(a0, b0, accA[0][0], 0, 0, 0);
        accA[0][1] = __builtin_amdgcn_mfma_f32_16x16x32_bf16(a0, b1, accA[0][1], 0, 0, 0);
        accA[1][0] = __builtin_amdgcn_mfma_f32_16x16x32_bf16(a1, b0, accA[1][0], 0, 0, 0);
        accA[1][1] = __builtin_amdgcn_mfma_f32_16x16x32_bf16(a1, b1, accA[1][1], 0, 0, 0);
    }
    #pragma unroll
    for (int nt = 0; nt < 2; ++nt) {
        int ccol = w * 32 + nt * 16 + col;
        float bia = varh_b[ccol];
        #pragma unroll
        for (int mt = 0; mt < 2; ++mt)
            #pragma unroll
            for (int r = 0; r < 4; ++r) {
                int row = mt * 16 + kg * 4 + r;
                vh_s[row][ccol] = f2bf(fmaxf(accA[mt][nt][r] + bia, 0.f));
            }
    }
    __syncthreads();

    f32x4 accM[2], accV[2];
    #pragma unroll
    for (int mt = 0; mt < 2; ++mt) { accM[mt] = (f32x4){0.f,0.f,0.f,0.f}; accV[mt] = (f32x4){0.f,0.f,0.f,0.f}; }
    #pragma unroll
    for (int kc = 0; kc < 4; ++kc) {
        bf8v a0 = *(const bf8v*)&post_s[col][kc * 32 + kg * 8];
        bf8v a1 = *(const bf8v*)&post_s[16 + col][kc * 32 + kg * 8];
        bf8v v0 = *(const bf8v*)&vh_s[col][kc * 32 + kg * 8];
        bf8v v1 = *(const bf8v*)&vh_s[16 + col][kc * 32 + kg * 8];
        bf8v bm = *(const bf8v*)&decWt[(w * 16 + col) * 128 + kc * 32 + kg * 8];
        bf8v bv = *(const bf8v*)&varWt[(w * 16 + col) * 128 + kc * 32 + kg * 8];
        accM[0] = __builtin_amdgcn_mfma_f32_16x16x32_bf16(a0, bm, accM[0], 0, 0, 0);
        accM[1] = __builtin_amdgcn_mfma_f32_16x16x32_bf16(a1, bm, accM[1], 0, 0, 0);
        accV[0] = __builtin_amdgcn_mfma_f32_16x16x32_bf16(v0, bv, accV[0], 0, 0, 0);
        accV[1] = __builtin_amdgcn_mfma_f32_16x16x32_bf16(v1, bv, accV[1], 0, 0, 0);
    }
    {
        int ccol = w * 16 + col;
        float bm = dec_b[ccol];
        float bv = var_b[ccol];
        #pragma unroll
        for (int mt = 0; mt < 2; ++mt)
            #pragma unroll
            for (int r = 0; r < 4; ++r) {
                long row = row0 + mt * 16 + kg * 4 + r;
                out[row * 128 + ccol] = accM[mt][r] + bm;
                out[row * 128 + 64 + ccol] = elup1f(accV[mt][r] + bv);
            }
    }
}

extern "C" void kernel_launch(void* const* d_in, const int* in_sizes, int n_in,
                              void* d_out, int out_size, void* d_ws, size_t ws_size,
                              hipStream_t stream) {
    const float* obs     = (const float*)d_in[0];
    const float* enc_W   = (const float*)d_in[1];
    const float* enc_b   = (const float*)d_in[2];
    const float* wmean_W = (const float*)d_in[3];
    const float* wmean_b = (const float*)d_in[4];
    const float* wcov_W  = (const float*)d_in[5];
    const float* wcov_b  = (const float*)d_in[6];
    const float* cW1     = (const float*)d_in[7];
    const float* cb1     = (const float*)d_in[8];
    const float* cW2     = (const float*)d_in[9];
    const float* cb2     = (const float*)d_in[10];
    const float* tm11    = (const float*)d_in[11];
    const float* tm12    = (const float*)d_in[12];
    const float* tm21    = (const float*)d_in[13];
    const float* tm22    = (const float*)d_in[14];
    const float* log_tc  = (const float*)d_in[15];
    const float* dec_W   = (const float*)d_in[16];
    const float* dec_b   = (const float*)d_in[17];
    const float* varh_W  = (const float*)d_in[18];
    const float* varh_b  = (const float*)d_in[19];
    const float* var_W   = (const float*)d_in[20];
    const float* var_b   = (const float*)d_in[21];

    float* out = (float*)d_out;
    float* ws = (float*)d_ws;
    float* wm_ws    = ws;                 // 786432
    float* wc_ws    = ws + 786432;        // 786432
    float* post_ws  = ws + 1572864;       // 1572864
    float* basis_ws = ws + 3145728;       // 28672
    unsigned short* encWt_bf  = (unsigned short*)(ws + 3174400);  // 65536 sh
    unsigned short* w2t_bf    = (unsigned short*)(ws + 3207168);  // 65536 sh
    unsigned short* varhWt_bf = (unsigned short*)(ws + 3239936);  // 16384 sh
    unsigned short* decWt_bf  = (unsigned short*)(ws + 3248128);  // 8192 sh
    unsigned short* varWt_bf  = (unsigned short*)(ws + 3252224);  // 8192 sh

    size_t dyn = (size_t)(6144 + 6144 + 12288) * sizeof(float);  // 98304 B
    (void)hipFuncSetAttribute((const void*)scan_kernel,
                              hipFuncAttributeMaxDynamicSharedMemorySize,
                              (int)dyn);

    prep_all<<<752, 256, 0, stream>>>(tm11, tm12, tm21, tm22, enc_W, wmean_W, wcov_W,
                                      varh_W, dec_W, var_W, basis_ws,
                                      encWt_bf, w2t_bf, varhWt_bf, decWt_bf, varWt_bf);
    encoder_mfma<<<384, 256, 0, stream>>>(obs, encWt_bf, enc_b, w2t_bf,
                                          wmean_b, wcov_b, wm_ws, wc_ws);
    scan_kernel<<<128, 256, dyn, stream>>>(wm_ws, wc_ws, cW1, cb1, cW2, cb2,
                                           basis_ws, log_tc, post_ws);
    decoder_mfma<<<384, 256, 0, stream>>>(post_ws, decWt_bf, dec_b, varhWt_bf, varh_b,
                                          varWt_bf, var_b, out);
}